// Round 2
// baseline (63.985 us; speedup 1.0000x reference)
//
#include <hip/hip_runtime.h>

// Problem constants (match reference)
#define PP 32   // patches
#define SS 4
#define CC 64
#define HH 128
#define WW 128
#define NC 32   // channels kept per patch
#define OO 32   // adaptive pool output size (MIN_SIZE)

// One 128-thread block per (p, s, c) crop.
// For each output row o: lane t computes the vertical sum of column t over the
// bin's rows (coalesced: consecutive lanes -> consecutive addresses), stages
// column sums in LDS, then lanes 0..31 reduce horizontal bins and store.
__global__ __launch_bounds__(128) void patch_pool_kernel(
    const float* __restrict__ input,     // [P,S,C,H,W]
    const int*   __restrict__ size_raw,  // [P]
    const int*   __restrict__ pix,       // [P]
    const int*   __restrict__ channels,  // [P,NC]
    float*       __restrict__ out)       // [P,S,NC,O,O]
{
    const int blk = blockIdx.x;          // (p*S+s)*NC + c
    const int c = blk & (NC - 1);
    const int s = (blk >> 5) & (SS - 1);
    const int p = blk >> 7;
    const int t = threadIdx.x;

    // Per-patch crop parameters (scalar per block)
    const int size = size_raw[p] + OO;          // [32, 128]
    const int wr = WW - size + 1;
    const int hr = HH - size + 1;
    const int pm = pix[p] % (wr * hr);
    const int offy = pm / wr;
    const int offx = pm - offy * wr;
    const int ch = channels[p * NC + c];

    const float* base = input
        + ((size_t)((p * SS + s) * CC + ch)) * (HH * WW)
        + offy * WW + offx;

    __shared__ float colsum[HH];

    #pragma unroll 1
    for (int o = 0; o < OO; ++o) {
        const int sy = (o * size) >> 5;
        const int ey = ((o + 1) * size + 31) >> 5;

        float acc = 0.0f;
        if (t < size) {
            const float* col = base + sy * WW + t;
            for (int y = sy; y < ey; ++y) {
                acc += *col;
                col += WW;
            }
        }
        colsum[t] = acc;
        __syncthreads();

        if (t < OO) {
            const int sx = (t * size) >> 5;
            const int ex = ((t + 1) * size + 31) >> 5;
            float a = 0.0f;
            for (int x = sx; x < ex; ++x) a += colsum[x];
            const float cnt = (float)((ey - sy) * (ex - sx));
            out[(size_t)blk * (OO * OO) + o * OO + t] = a / cnt;
        }
        __syncthreads();
    }
}

extern "C" void kernel_launch(void* const* d_in, const int* in_sizes, int n_in,
                              void* d_out, int out_size, void* d_ws, size_t ws_size,
                              hipStream_t stream) {
    const float* input    = (const float*)d_in[0];
    const int*   size_raw = (const int*)d_in[1];
    const int*   pix      = (const int*)d_in[2];
    const int*   channels = (const int*)d_in[3];
    float*       out      = (float*)d_out;

    const int grid = PP * SS * NC;   // 4096 blocks
    patch_pool_kernel<<<grid, 128, 0, stream>>>(input, size_raw, pix, channels, out);
}